// Round 19
// baseline (13.013 us; speedup 1.0000x reference)
//
#include <hip/hip_runtime.h>
#include <math.h>

#define BS 4
#define CH 256
#define XD 1024
#define N 128
#define NP 8128
#define NSTRIP 32              // column-groups of 4 per batch
#define STRIPBLK (BS * NSTRIP) // 128 strip blocks
#define NPASSBLK 128           // pass blocks, 8 rows each -> total 256 = 1/CU
#define TWO_PI_F 6.283185307179586f
#define PADR 66                // u32 row stride (64 ch-pairs + 2 pad)

typedef __fp16 h2v __attribute__((ext_vector_type(2)));

__device__ __forceinline__ h2v u2h(unsigned u) {
  union { unsigned u; h2v h; } c; c.u = u; return c.h;
}
__device__ __forceinline__ unsigned h2u(h2v h) {
  union { unsigned u; h2v h; } c; c.h = h; return c.u;
}

// ---------------------------------------------------------------------------
// SINGLE kernel, 256 blocks x 256 threads (exactly 1 block/CU -- R17's only
// defect was 384 blocks = 1.5 scheduling rounds), zero cross-block comm.
//
// Math: v_new[j]/x_new[j] depend only on COLUMN j's mask bits, and
// mask[i,j] > 0.5 requires u_x = exp(-x_r) > 0.5 (since v_r/v_r_max <= 1),
// i.e. x_r^2 < ln(2)^2 -- a purely x-local test. A block owning columns J
// that verifies x_r^2 >= threshold for all (i, J) writes its columns with
// the exact no-collision closed form out = x + 0.5*a, independent of v_r_max.
//
//  blocks [0,128): strip role. (b,g) owns kinetic columns [4g,4g+4) of batch
//    b. Stages x-dims as f16 pairs (2 channel-halves; x ONLY -- the predicate
//    needs no a), dot2-computes x_r^2 for 128 x 4 pairs, predicate
//    any(i!=j && x_r^2 < 2.0) [conservative vs 0.48: f16 margin]. Fast path
//    (always, this data): write 4 cols x 256 ch = x + 0.5*a. Slow path
//    (never): exact f32 self-contained recompute; columns exclusively owned.
//  blocks [128,256): pass role. 8 rows each, ONLY non-dims positions
//    (nibble mask; all-dims quads skipped). Disjoint from strip writes.
// ---------------------------------------------------------------------------
__global__ __launch_bounds__(256) void k_all(
    const float* __restrict__ x, const float* __restrict__ a,
    const float* __restrict__ ru, const int* __restrict__ dims,
    float* __restrict__ out) {
  int bid = blockIdx.x, t = threadIdx.x;
  __shared__ unsigned sX[N][PADR];   // f16-pair packed x-dims, one ch-half
  __shared__ unsigned inset[XD / 32];
  __shared__ int dsh[N];
  __shared__ int flg[2];             // [0]=dims contiguous, [1]=candidate
  __shared__ float red[256];
  __shared__ unsigned maskb[4][4];   // slow path: 4 cols x 128 mask bits
  __shared__ float vrcol[4][N];      // slow path: vr for my 4 columns

  if (bid >= STRIPBLK) {
    // ---------------- pass role: non-dims positions only ----------------
    int pb = bid - STRIPBLK;  // 0..127
    if (t < XD / 32) inset[t] = 0u;
    __syncthreads();
    if (t < N) atomicOr(&inset[dims[t] >> 5], 1u << (dims[t] & 31));
    __syncthreads();
    int row0 = pb << 3;
#pragma unroll
    for (int r = 0; r < 8; ++r) {
      int row = row0 + r;
      const float4* x4 = (const float4*)(x + (size_t)row * XD);
      const float4* a4 = (const float4*)(a + (size_t)row * XD);
      float4* o4 = (float4*)(out + (size_t)row * XD);
      int e = t;  // float4 index 0..255
      unsigned nib = (inset[e >> 3] >> ((e & 7) * 4)) & 0xFu;
      if (nib == 0u) {  // pure non-dims quad
        float4 xv = x4[e], av = a4[e];
        o4[e] = make_float4(xv.x + av.x, xv.y + av.y, xv.z + av.z, xv.w + av.w);
      } else if (nib != 0xFu) {  // mixed quad (general dims)
#pragma unroll
        for (int c2 = 0; c2 < 4; ++c2) {
          if (!(nib & (1u << c2))) {
            size_t off = (size_t)row * XD + 4 * e + c2;
            out[off] = x[off] + a[off];
          }
        }
      }  // nib==0xF: all-dims quad, strip-owned
    }
    return;
  }

  // ---------------- strip role ----------------
  int b = bid / NSTRIP, g = bid % NSTRIP;
  if (t == 0) { flg[0] = 1; flg[1] = 0; }
  __syncthreads();
  if (t < N) {
    int d = dims[t];
    dsh[t] = d;
    if (d != t) atomicAnd(&flg[0], 0);
  }
  __syncthreads();
  int contig = flg[0];
  const float* xb = x + (size_t)b * CH * XD;

  // predicate over 2 channel-halves: pairs (i, j=4g+(t&3)), i = t>>2, +64
  int jj = 4 * g + (t & 3);
  int i1 = t >> 2, i2 = i1 + 64;
  float acc1 = 0.f, acc2 = 0.f;
  for (int h = 0; h < 2; ++h) {
    __syncthreads();  // protect previous half's readers
    if (contig) {
      for (int u = t; u < 64 * 32; u += 256) {  // (ch-pair-local, dim-quad)
        int cpl = u >> 5, q = u & 31;
        int cp = (h << 6) + cpl;
        float4 f0 = *(const float4*)&xb[(size_t)(2 * cp) * XD + 4 * q];
        float4 f1 = *(const float4*)&xb[(size_t)(2 * cp + 1) * XD + 4 * q];
        sX[4 * q + 0][cpl] = h2u(__builtin_amdgcn_cvt_pkrtz(f0.x, f1.x));
        sX[4 * q + 1][cpl] = h2u(__builtin_amdgcn_cvt_pkrtz(f0.y, f1.y));
        sX[4 * q + 2][cpl] = h2u(__builtin_amdgcn_cvt_pkrtz(f0.z, f1.z));
        sX[4 * q + 3][cpl] = h2u(__builtin_amdgcn_cvt_pkrtz(f0.w, f1.w));
      }
    } else {  // general gather: 2 threads per dim, 32 ch-pairs each
      int dd = t & 127, sub = t >> 7;
      int d = dsh[dd];
      for (int m = 0; m < 32; ++m) {
        int cpl = sub * 32 + m;
        int cp = (h << 6) + cpl;
        float f0 = xb[(size_t)(2 * cp) * XD + d];
        float f1 = xb[(size_t)(2 * cp + 1) * XD + d];
        sX[dd][cpl] = h2u(__builtin_amdgcn_cvt_pkrtz(f0, f1));
      }
    }
    __syncthreads();
#pragma unroll 8
    for (int cq = 0; cq < 16; ++cq) {
      uint4 xj = *(const uint4*)&sX[jj][cq * 4];
      uint4 u1 = *(const uint4*)&sX[i1][cq * 4];
      uint4 u2 = *(const uint4*)&sX[i2][cq * 4];
      h2v d;
      d = u2h(u1.x) - u2h(xj.x); acc1 = __builtin_amdgcn_fdot2(d, d, acc1, false);
      d = u2h(u1.y) - u2h(xj.y); acc1 = __builtin_amdgcn_fdot2(d, d, acc1, false);
      d = u2h(u1.z) - u2h(xj.z); acc1 = __builtin_amdgcn_fdot2(d, d, acc1, false);
      d = u2h(u1.w) - u2h(xj.w); acc1 = __builtin_amdgcn_fdot2(d, d, acc1, false);
      d = u2h(u2.x) - u2h(xj.x); acc2 = __builtin_amdgcn_fdot2(d, d, acc2, false);
      d = u2h(u2.y) - u2h(xj.y); acc2 = __builtin_amdgcn_fdot2(d, d, acc2, false);
      d = u2h(u2.z) - u2h(xj.z); acc2 = __builtin_amdgcn_fdot2(d, d, acc2, false);
      d = u2h(u2.w) - u2h(xj.w); acc2 = __builtin_amdgcn_fdot2(d, d, acc2, false);
    }
  }
  // candidate: u_x > 0.5 possible, i.e. x_r^2 < ln2^2 (=0.48; 2.0 = f16 margin)
  bool cand = ((i1 != jj) && (acc1 < 2.0f)) || ((i2 != jj) && (acc2 < 2.0f));
  if (__any(cand)) {
    if ((t & 63) == 0) atomicOr(&flg[1], 1);
  }
  __syncthreads();

  if (!flg[1]) {
    // ---- fast path: my 4 columns are provably collision-free ----
    int row = (b << 8) + t;  // one channel-row per thread
    if (contig) {
      const float4* x4 = (const float4*)(x + (size_t)row * XD);
      const float4* a4 = (const float4*)(a + (size_t)row * XD);
      float4 xv = x4[g], av = a4[g];
      ((float4*)(out + (size_t)row * XD))[g] =
          make_float4(fmaf(0.5f, av.x, xv.x), fmaf(0.5f, av.y, xv.y),
                      fmaf(0.5f, av.z, xv.z), fmaf(0.5f, av.w, xv.w));
    } else {
#pragma unroll
      for (int k = 0; k < 4; ++k) {
        size_t off = (size_t)row * XD + dsh[4 * g + k];
        out[off] = fmaf(0.5f, a[off], x[off]);
      }
    }
    return;
  }

  // ---- slow path: exact f32, fully self-contained (never taken here) ----
  const float* ab = a + (size_t)b * CH * XD;
  // 1) v_r_max over all upper-triangle pairs of batch b (global reads, f32)
  float vmx = 0.f;
  for (int cell = t; cell < N * N; cell += 256) {
    int i = cell >> 7, j = cell & 127;
    if (i < j) {
      int di = dsh[i], dj = dsh[j];
      float s = 0.f;
      for (int c = 0; c < CH; ++c) {
        float dv = ab[(size_t)c * XD + di] - ab[(size_t)c * XD + dj];
        s = fmaf(dv, dv, s);
      }
      vmx = fmaxf(vmx, s);
    }
  }
  red[t] = vmx;
  __syncthreads();
  for (int s2 = 128; s2 > 0; s2 >>= 1) {
    if (t < s2) red[t] = fmaxf(red[t], red[t + s2]);
    __syncthreads();
  }
  float vrmax = sqrtf(red[0]);
  float inv = vrmax > 0.f ? 1.f / vrmax : 0.f;  // vrmax==0 -> all-false mask

  // 2) exact masks + vr for my 4 columns
  if (t < 16) maskb[t >> 2][t & 3] = 0u;
  __syncthreads();
  for (int u = t; u < 4 * N; u += 256) {
    int kc = u >> 7, i = u & 127;
    int j = 4 * g + kc;
    int di = dsh[i], dj = dsh[j];
    float sx2 = 0.f, sv2 = 0.f;
    for (int c = 0; c < CH; ++c) {
      float dx = xb[(size_t)c * XD + di] - xb[(size_t)c * XD + dj];
      sx2 = fmaf(dx, dx, sx2);
      float dv = ab[(size_t)c * XD + di] - ab[(size_t)c * XD + dj];
      sv2 = fmaf(dv, dv, sv2);
    }
    float vr = sqrtf(sv2);
    float ux = expf(-sqrtf(sx2));
    vrcol[kc][i] = vr;
    if (vr * inv * ux > 0.5f) atomicOr(&maskb[kc][i >> 5], 1u << (i & 31));
  }
  __syncthreads();

  // 3) per-channel update for my 4 columns (thread = channel)
  {
    int c = t;
    int bc = (b << 8) + c;
    const float* rub = ru + (size_t)bc * NP;
#pragma unroll
    for (int kc = 0; kc < 4; ++kc) {
      int j = 4 * g + kc;
      int dj = dsh[j];
      float xxj = x[(size_t)bc * XD + dj];
      float vvj = a[(size_t)bc * XD + dj];
      float S = 0.f, sumV = 0.f, sumX = 0.f, R = 0.f;
      for (int w = 0; w < 4; ++w) {
        unsigned bits = maskb[kc][w];
        while (bits) {
          int i = (w << 5) + __ffs(bits) - 1;
          bits &= bits - 1;
          S += 1.f;
          int di = dsh[i];
          sumV += a[(size_t)bc * XD + di];
          sumX += x[(size_t)bc * XD + di];
          float vrv = vrcol[kc][i];
          int p;
          float sgn;
          if (i < j) {
            p = i * N - ((i * (i + 1)) >> 1) + (j - i - 1);
            sgn = 1.f;
          } else {
            p = j * N - ((j * (j + 1)) >> 1) + (i - j - 1);
            sgn = -1.f;
          }
          R += sgn * TWO_PI_F * vrv * rub[p];
        }
      }
      float v_new = vvj + 0.5f * S * vvj - 0.5f * sumV + R;
      float x_new = 0.5f * xxj + 0.5f * (xxj + sumX) / (S + 1.f) + 0.5f * v_new;
      out[(size_t)bc * XD + dj] = x_new;
    }
  }
}

extern "C" void kernel_launch(void* const* d_in, const int* in_sizes, int n_in,
                              void* d_out, int out_size, void* d_ws, size_t ws_size,
                              hipStream_t stream) {
  const float* x = (const float*)d_in[0];
  // d_in[1] = v : unused by the reference computation
  const float* a = (const float*)d_in[2];
  const float* ru = (const float*)d_in[3];
  const int* dims = (const int*)d_in[4];
  float* out = (float*)d_out;
  // d_ws unused: the column-local decomposition needs no workspace.

  k_all<<<STRIPBLK + NPASSBLK, 256, 0, stream>>>(x, a, ru, dims, out);
}